// Round 3
// baseline (3229.564 us; speedup 1.0000x reference)
//
#include <hip/hip_runtime.h>
#include <math.h>

// FISTA data-consistency with masked multi-coil 2D FFT operator.
// B=4, C=16, H=W=384.
// Register FFT: 384 = 6 (regs) x 64 (lanes); DIF leaves bit-reversed-permuted
// frequencies; mask is pre-permuted; DIT consumes permuted order (free).
// Loop restructured: iter-1 is elementwise (y0=0); P3+P1 fused (k_p31).

#define NN 384
#define BB 4
#define CC 16
#define NITER 20
#define LNPAD 432   // old LDS path (precompute only)

__device__ __forceinline__ int LID(int i) { return i + (i >> 3); }

__device__ __forceinline__ float2 cmulf(float2 a, float2 b) {
  return make_float2(a.x * b.x - a.y * b.y, a.x * b.y + a.y * b.x);
}

template<int DIR>
__device__ __forceinline__ void dft4(float2* v) {
  float ax = v[0].x + v[2].x, ay = v[0].y + v[2].y;
  float bx = v[0].x - v[2].x, by = v[0].y - v[2].y;
  float cx = v[1].x + v[3].x, cy = v[1].y + v[3].y;
  float dx = v[1].x - v[3].x, dy = v[1].y - v[3].y;
  float dix, diy;
  if (DIR < 0) { dix = dy; diy = -dx; }
  else         { dix = -dy; diy = dx; }
  v[0] = make_float2(ax + cx, ay + cy);
  v[2] = make_float2(ax - cx, ay - cy);
  v[1] = make_float2(bx + dix, by + diy);
  v[3] = make_float2(bx - dix, by - diy);
}

template<int DIR>
__device__ __forceinline__ void dft6(float2* v) {
  const float S3 = 0.86602540378443864676f;
  const float wc[6]  = {1.f, 0.5f, -0.5f, -1.f, -0.5f, 0.5f};
  const float wsf[6] = {0.f, -S3, -S3, 0.f, S3, S3};  // forward (e^{-2pi i k/6})
  float2 o[6];
#pragma unroll
  for (int k = 0; k < 6; ++k) {
    float ox = v[0].x, oy = v[0].y;
#pragma unroll
    for (int r = 1; r < 6; ++r) {
      int idx = (r * k) % 6;
      float wr_ = wc[idx];
      float wi_ = (DIR < 0) ? wsf[idx] : -wsf[idx];
      ox += v[r].x * wr_ - v[r].y * wi_;
      oy += v[r].x * wi_ + v[r].y * wr_;
    }
    o[k] = make_float2(ox, oy);
  }
#pragma unroll
  for (int k = 0; k < 6; ++k) v[k] = o[k];
}

// ---------------- register FFT machinery (iteration path) ------------------

// radix-2 DIF FFT-64 across lanes; natural in -> bit-reversed out.
template<int SIGN>
__device__ __forceinline__ void dif64(float2 v[6], int t) {
#pragma unroll
  for (int hs = 5; hs >= 0; --hs) {
    int h = 1 << hs;
    float ang = (float)SIGN * 3.14159265358979323846f / (float)h * (float)(t & (h - 1));
    float sn, cs; __sincosf(ang, &sn, &cs);
    bool hi = (t & h) != 0;
#pragma unroll
    for (int r = 0; r < 6; ++r) {
      float2 o;
      o.x = __shfl_xor(v[r].x, h);
      o.y = __shfl_xor(v[r].y, h);
      float dx = o.x - v[r].x, dy = o.y - v[r].y;
      float2 tw = make_float2(dx * cs - dy * sn, dx * sn + dy * cs);
      v[r] = hi ? tw : make_float2(v[r].x + o.x, v[r].y + o.y);
    }
  }
}

// radix-2 DIT FFT-64 across lanes; bit-reversed in -> natural out.
template<int SIGN>
__device__ __forceinline__ void dit64(float2 v[6], int t) {
#pragma unroll
  for (int hs = 0; hs < 6; ++hs) {
    int h = 1 << hs;
    float ang = (float)SIGN * 3.14159265358979323846f / (float)h * (float)(t & (h - 1));
    float sn, cs; __sincosf(ang, &sn, &cs);
    bool hi = (t & h) != 0;
#pragma unroll
    for (int r = 0; r < 6; ++r) {
      float2 bt = v[r];
      if (hi) bt = make_float2(v[r].x * cs - v[r].y * sn, v[r].x * sn + v[r].y * cs);
      float2 o;
      o.x = __shfl_xor(bt.x, h);
      o.y = __shfl_xor(bt.y, h);
      v[r] = hi ? make_float2(o.x - bt.x, o.y - bt.y)
                : make_float2(bt.x + o.x, bt.y + o.y);
    }
  }
}

// FWD: natural input (v[k]=x[t+64k]) -> permuted output (s=t+64r holds X[P(s)])
template<int SIGN>
__device__ __forceinline__ void fwd384(float2 v[6], int t) {
  dft6<SIGN>(v);
  float ang = (float)SIGN * 6.28318530717958647692f / 384.0f * (float)t;
  float sn, cs; __sincosf(ang, &sn, &cs);
  float2 w = make_float2(cs, sn), wr = w;
#pragma unroll
  for (int r = 1; r < 6; ++r) { v[r] = cmulf(v[r], wr); wr = cmulf(wr, w); }
  dif64<SIGN>(v, t);
}

// BWD: permuted input -> natural output; unnormalized inverse of fwd384.
template<int SIGN>
__device__ __forceinline__ void bwd384(float2 v[6], int t) {
  dit64<SIGN>(v, t);
  float ang = (float)SIGN * 6.28318530717958647692f / 384.0f * (float)t;
  float sn, cs; __sincosf(ang, &sn, &cs);
  float2 w = make_float2(cs, sn), wr = w;
#pragma unroll
  for (int r = 1; r < 6; ++r) { v[r] = cmulf(v[r], wr); wr = cmulf(wr, w); }
  dft6<SIGN>(v);
}

// ---------------- old LDS fft384 (precompute kernels only) -----------------
template<int R, int NS, int DIR>
__device__ __forceinline__ void fft_stage(const float2* S, float2* D, int t) {
  constexpr int NR = NN / R;
  constexpr float TWOPI = 6.28318530717958647692f;
#pragma unroll
  for (int rep = 0; rep < (NR + 63) / 64; ++rep) {
    int j = t + rep * 64;
    if (j < NR) {
      float2 v[R];
#pragma unroll
      for (int r = 0; r < R; ++r) v[r] = S[LID(j + r * NR)];
      if constexpr (NS > 1) {
        float ang = (float)DIR * (TWOPI / (float)(NS * R)) * (float)(j % NS);
        float sv, cv;
        __sincosf(ang, &sv, &cv);
        float2 w = make_float2(cv, sv);
        float2 wr = w;
#pragma unroll
        for (int r = 1; r < R; ++r) { v[r] = cmulf(v[r], wr); wr = cmulf(wr, w); }
      }
      if constexpr (R == 4) dft4<DIR>(v); else dft6<DIR>(v);
      int base = (j / NS) * (NS * R) + (j % NS);
#pragma unroll
      for (int r = 0; r < R; ++r) D[LID(base + r * NS)] = v[r];
    }
  }
}

template<int DIR>
__device__ __forceinline__ void fft384(float2* A, float2* Bf, int t) {
  fft_stage<4, 1,  DIR>(A,  Bf, t); __syncthreads();
  fft_stage<4, 4,  DIR>(Bf, A,  t); __syncthreads();
  fft_stage<4, 16, DIR>(A,  Bf, t); __syncthreads();
  fft_stage<6, 64, DIR>(Bf, A,  t); __syncthreads();
}

// ---------------- E: iteration 1 (y0 = 0 -> grad = -cst), elementwise ------
__global__ __launch_bounds__(256) void k_e(const float2* __restrict__ cstb,
                                           const float* __restrict__ zk,
                                           const float* __restrict__ lamp,
                                           float2* __restrict__ xbuf,
                                           float2* __restrict__ ybuf) {
  long i = (long)blockIdx.x * 256 + threadIdx.x;
  long b = i / (NN * NN);
  long p = i % (NN * NN);
  float lamv = lamp[0];
  float2 cs = cstb[i];
  float zr = zk[(b * 2 + 0) * (long)(NN * NN) + p];
  float zi = zk[(b * 2 + 1) * (long)(NN * NN) + p];
  float xr = cs.x - lamv * (cs.x - zr);
  float xi = cs.y - lamv * (cs.y - zi);
  xr = fmaxf(xr, 0.f);
  xi = fmaxf(xi, 0.f);
  float2 x = make_float2(xr, xi);
  xbuf[i] = x;
  ybuf[i] = x;   // beta0 = 0, x0 = 0
}

// ---------------- P1: row FFT of coil*y -> W1 (permuted-x storage) ---------
// grid B*C*384/4, 256 thr; one wave per row; no LDS, no barriers. (once)
__global__ __launch_bounds__(256) void k_p1(const float2* __restrict__ ybuf,
                                            const float* __restrict__ csm,
                                            float2* __restrict__ W1) {
  int t = threadIdx.x & 63;
  int w = threadIdx.x >> 6;
  long gl = (long)blockIdx.x * 4 + w;       // (b*C + c)*384 + y
  int y = (int)(gl % NN);
  long bc = gl / NN;
  long b = bc >> 4, c = bc & 15;
  long rowoff = (long)y * NN;
  const float2* yrow = ybuf + b * (long)(NN * NN) + rowoff;
  const float* crow_re = csm + (b * 2 * CC + c) * (long)(NN * NN) + rowoff;
  const float* crow_im = crow_re + (long)CC * NN * NN;
  float2 v[6];
#pragma unroll
  for (int k = 0; k < 6; ++k) {
    int x = t + 64 * k;
    float2 yv = yrow[x];
    float cre = crow_re[x], cim = crow_im[x];
    v[k] = make_float2(yv.x * cre - yv.y * cim, yv.x * cim + yv.y * cre);
  }
  fwd384<-1>(v, t);
  float2* orow = W1 + gl * NN;
#pragma unroll
  for (int r = 0; r < 6; ++r) orow[t + 64 * r] = v[r];
}

// ---------------- P2: col FFT -> mask -> col IFFT, in-place on W1 ----------
// grid B*C*(N/8), 256 thr. 8-column planar transpose tile (24.9 KB LDS).
// Each wave owns 2 disjoint columns -> exactly 2 __syncthreads per block.
#define P2PAD 389
__global__ __launch_bounds__(256) void k_p2(float2* __restrict__ W1,
                                            const unsigned char* __restrict__ maskPT) {
  __shared__ float ldsR[8][P2PAD];
  __shared__ float ldsI[8][P2PAD];
  int tid = threadIdx.x;
  int xt = blockIdx.x % (NN / 8);
  long bc = blockIdx.x / (NN / 8);
  long b = bc >> 4;
  int s0 = xt * 8;
  long sbase = bc * (long)(NN * NN);
#pragma unroll
  for (int k = 0; k < 12; ++k) {
    int e = tid + k * 256; int y = e >> 3; int c = e & 7;
    float2 val = W1[sbase + (long)y * NN + s0 + c];
    ldsR[c][y] = val.x; ldsI[c][y] = val.y;
  }
  __syncthreads();
  int w = tid >> 6, t = tid & 63;
  const unsigned char* mb = maskPT + b * (long)(NN * NN);
#pragma unroll
  for (int i = 0; i < 2; ++i) {
    int c = w * 2 + i;
    float2 v[6];
#pragma unroll
    for (int k = 0; k < 6; ++k)
      v[k] = make_float2(ldsR[c][t + 64 * k], ldsI[c][t + 64 * k]);
    fwd384<-1>(v, t);
    const unsigned char* mcol = mb + (long)(s0 + c) * NN;
#pragma unroll
    for (int r = 0; r < 6; ++r) {
      float mv = (float)mcol[t + 64 * r];
      v[r].x *= mv; v[r].y *= mv;
    }
    bwd384<1>(v, t);
#pragma unroll
    for (int k = 0; k < 6; ++k) {
      ldsR[c][t + 64 * k] = v[k].x * (1.0f / NN);
      ldsI[c][t + 64 * k] = v[k].y * (1.0f / NN);
    }
  }
  __syncthreads();
#pragma unroll
  for (int k = 0; k < 12; ++k) {
    int e = tid + k * 256; int y = e >> 3; int c = e & 7;
    W1[sbase + (long)y * NN + s0 + c] = make_float2(ldsR[c][y], ldsI[c][y]);
  }
}

// ------- P31: row IFFT + conj(coil) reduce + FISTA update + next fwd -------
// grid B*384 blocks, 256 thr; wave w handles coils 4w..4w+3.
__global__ __launch_bounds__(256) void k_p31(float2* __restrict__ W1,
                                             const float* __restrict__ csm,
                                             const float2* __restrict__ cstb,
                                             const float* __restrict__ zk,
                                             const float* __restrict__ lamp,
                                             float2* __restrict__ xbuf,
                                             float2* __restrict__ ybuf,
                                             float beta, int do_fwd) {
  __shared__ float2 part[4][NN];
  __shared__ float2 yrow[NN];
  int tid = threadIdx.x;
  int w = tid >> 6, t = tid & 63;
  long gl = blockIdx.x;            // b*384 + y
  long b = gl / NN;
  int y = (int)(gl % NN);
  long rowoff = (long)y * NN;
  float2 acc[6];
#pragma unroll
  for (int k = 0; k < 6; ++k) acc[k] = make_float2(0.f, 0.f);
#pragma unroll
  for (int ci = 0; ci < 4; ++ci) {
    int c = w * 4 + ci;
    const float2* row = W1 + ((b * CC + c) * (long)NN + y) * NN;
    float2 v[6];
#pragma unroll
    for (int r = 0; r < 6; ++r) v[r] = row[t + 64 * r];
    bwd384<1>(v, t);
    const float* cre = csm + (b * 2 * CC + c) * (long)(NN * NN) + rowoff;
    const float* cim = cre + (long)CC * NN * NN;
#pragma unroll
    for (int k = 0; k < 6; ++k) {
      int x = t + 64 * k;
      float a = cre[x], bb = cim[x];
      acc[k].x += (a * v[k].x + bb * v[k].y);
      acc[k].y += (a * v[k].y - bb * v[k].x);
    }
  }
#pragma unroll
  for (int k = 0; k < 6; ++k) part[w][t + 64 * k] = acc[k];
  __syncthreads();
  float lamv = lamp[0];
  long pbase = b * (long)(NN * NN) + rowoff;
  for (int e = tid; e < NN; e += 256) {
    float Qx = (part[0][e].x + part[1][e].x + part[2][e].x + part[3][e].x) * (1.0f / NN);
    float Qy = (part[0][e].y + part[1][e].y + part[2][e].y + part[3][e].y) * (1.0f / NN);
    float2 yv = ybuf[pbase + e];
    float2 cs = cstb[pbase + e];
    float2 xo = xbuf[pbase + e];
    float zr = zk[(b * 2 + 0) * (long)(NN * NN) + rowoff + e];
    float zi = zk[(b * 2 + 1) * (long)(NN * NN) + rowoff + e];
    float xr = yv.x - (Qx - cs.x);
    float xi = yv.y - (Qy - cs.y);
    xr = xr - lamv * (xr - zr);
    xi = xi - lamv * (xi - zi);
    xr = fmaxf(xr, 0.f);
    xi = fmaxf(xi, 0.f);
    xbuf[pbase + e] = make_float2(xr, xi);
    float2 yn = make_float2(xr + beta * (xr - xo.x), xi + beta * (xi - xo.y));
    ybuf[pbase + e] = yn;
    yrow[e] = yn;
  }
  __syncthreads();
  if (do_fwd) {
#pragma unroll
    for (int ci = 0; ci < 4; ++ci) {
      int c = w * 4 + ci;
      const float* cre = csm + (b * 2 * CC + c) * (long)(NN * NN) + rowoff;
      const float* cim = cre + (long)CC * NN * NN;
      float2 u[6];
#pragma unroll
      for (int k = 0; k < 6; ++k) {
        int x = t + 64 * k;
        float2 yv = yrow[x];
        float a = cre[x], bb = cim[x];
        u[k] = make_float2(yv.x * a - yv.y * bb, yv.x * bb + yv.y * a);
      }
      fwd384<-1>(u, t);
      float2* orow = W1 + ((b * CC + c) * (long)NN + y) * NN;
#pragma unroll
      for (int r = 0; r < 6; ++r) orow[t + 64 * r] = u[r];
    }
  }
}

// ---------------- mask permutation precompute (one-time) -------------------
// maskPT[b][sx][sy] = mask[b][P(sy)][P(sx)], P(s) = (s>>6) + 6*brev6(s&63)
__global__ __launch_bounds__(256) void k_mpre(const int* __restrict__ mask,
                                              unsigned char* __restrict__ maskPT) {
  long i = (long)blockIdx.x * 256 + threadIdx.x;
  long b = i / (NN * NN);
  int rem = (int)(i % (NN * NN));
  int sx = rem / NN, sy = rem % NN;
  int fx = (sx >> 6) + 6 * (int)(__brev((unsigned)(sx & 63)) >> 26);
  int fy = (sy >> 6) + 6 * (int)(__brev((unsigned)(sy & 63)) >> 26);
  maskPT[i] = (unsigned char)mask[b * (long)(NN * NN) + (long)fy * NN + fx];
}

// ---------------- precompute: cst = (sum_c conj(coil)) * IFFT2(m*b) --------
__global__ __launch_bounds__(256) void k_preA(const float* __restrict__ x0,
                                              const int* __restrict__ mask,
                                              float2* __restrict__ T) {
  __shared__ float2 U[4][LNPAD], V[4][LNPAD];
  int tid = threadIdx.x;
  int line = tid >> 6, t = tid & 63;
  long gl0 = (long)blockIdx.x * 4;
#pragma unroll
  for (int k = 0; k < 6; ++k) {
    int e = tid + k * 256; int l = e / NN; int x = e % NN;
    long gl = gl0 + l;
    long b = gl / NN;
    int y = (int)(gl % NN);
    long pidx = (long)y * NN + x;
    float mv = (float)mask[b * (long)(NN * NN) + pidx];
    float br = x0[(b * 2 + 0) * (long)(NN * NN) + pidx] * mv;
    float bi = x0[(b * 2 + 1) * (long)(NN * NN) + pidx] * mv;
    U[l][LID(x)] = make_float2(br, bi);
  }
  __syncthreads();
  fft384<1>(U[line], V[line], t);
#pragma unroll
  for (int k = 0; k < 6; ++k) {
    int e = tid + k * 256; int l = e / NN; int x = e % NN;
    float2 u = U[l][LID(x)];
    T[(gl0 + l) * NN + x] = make_float2(u.x * (1.0f / NN), u.y * (1.0f / NN));
  }
}

__global__ __launch_bounds__(256) void k_preB(const float2* __restrict__ T,
                                              float2* __restrict__ r0) {
  __shared__ float2 tile[NN][17];
  __shared__ float2 U[4][LNPAD], V[4][LNPAD];
  int tid = threadIdx.x;
  int xt = blockIdx.x % (NN / 16);
  long b = blockIdx.x / (NN / 16);
  int x0c = xt * 16;
  long sbase = b * (long)(NN * NN);
#pragma unroll
  for (int k = 0; k < 24; ++k) {
    int e = tid + k * 256; int y = e >> 4; int c = e & 15;
    tile[y][c] = T[sbase + (long)y * NN + x0c + c];
  }
  __syncthreads();
  int line = tid >> 6, t = tid & 63;
  for (int g = 0; g < 4; ++g) {
#pragma unroll
    for (int k = 0; k < 6; ++k) {
      int e = tid + k * 256; int l = e / NN; int y = e % NN;
      U[l][LID(y)] = tile[y][4 * g + l];
    }
    __syncthreads();
    fft384<1>(U[line], V[line], t);
#pragma unroll
    for (int k = 0; k < 6; ++k) {
      int e = tid + k * 256; int l = e / NN; int y = e % NN;
      float2 u = U[l][LID(y)];
      tile[y][4 * g + l] = make_float2(u.x * (1.0f / NN), u.y * (1.0f / NN));
    }
    __syncthreads();
  }
#pragma unroll
  for (int k = 0; k < 24; ++k) {
    int e = tid + k * 256; int y = e >> 4; int c = e & 15;
    r0[sbase + (long)y * NN + x0c + c] = tile[y][c];
  }
}

__global__ __launch_bounds__(256) void k_preC(const float* __restrict__ csm,
                                              const float2* __restrict__ r0,
                                              float2* __restrict__ cstb) {
  long i = (long)blockIdx.x * 256 + threadIdx.x;
  long b = i / (NN * NN);
  long p = i % (NN * NN);
  float sr = 0.f, si = 0.f;
#pragma unroll
  for (int c = 0; c < CC; ++c) {
    sr += csm[(b * 2 * CC + c) * (long)(NN * NN) + p];
    si -= csm[((b * 2 + 1) * CC + c) * (long)(NN * NN) + p];
  }
  float2 r = r0[i];
  cstb[i] = make_float2(sr * r.x - si * r.y, sr * r.y + si * r.x);
}

__global__ __launch_bounds__(256) void k_out(const float2* __restrict__ xbuf,
                                             float* __restrict__ out) {
  long i = (long)blockIdx.x * 256 + threadIdx.x;
  long b = i / (NN * NN);
  long p = i % (NN * NN);
  float2 v = xbuf[i];
  out[(b * 2 + 0) * (long)(NN * NN) + p] = v.x;
  out[(b * 2 + 1) * (long)(NN * NN) + p] = v.y;
}

extern "C" void kernel_launch(void* const* d_in, const int* in_sizes, int n_in,
                              void* d_out, int out_size, void* d_ws, size_t ws_size,
                              hipStream_t stream) {
  const float* zk  = (const float*)d_in[0];
  const float* x0  = (const float*)d_in[1];
  const float* csm = (const float*)d_in[2];
  const float* lam = (const float*)d_in[3];
  const int*   msk = (const int*)d_in[4];
  float* out = (float*)d_out;

  // ws layout (float2 units): W1 [B*C*N*N] | y | x | cst | maskPT(uchar)
  size_t img = (size_t)BB * NN * NN;
  float2* W1   = (float2*)d_ws;
  float2* ybuf = W1 + (size_t)BB * CC * NN * NN;
  float2* xbuf = ybuf + img;
  float2* cstb = xbuf + img;
  unsigned char* maskPT = (unsigned char*)(cstb + img);
  float2* T  = W1;        // precompute scratch overlays W1
  float2* r0 = W1 + img;

  double tcur = 1.0;
  float betas[NITER];
  for (int i = 0; i < NITER; ++i) {
    double tn = (1.0 + sqrt(1.0 + 4.0 * tcur * tcur)) * 0.5;
    betas[i] = (float)((tcur - 1.0) / tn);
    tcur = tn;
  }

  k_mpre<<<(BB * NN * NN) / 256, 256, 0, stream>>>(msk, maskPT);
  k_preA<<<BB * NN / 4, 256, 0, stream>>>(x0, msk, T);
  k_preB<<<BB * (NN / 16), 256, 0, stream>>>(T, r0);
  k_preC<<<(BB * NN * NN) / 256, 256, 0, stream>>>(csm, r0, cstb);
  // iteration 1 (y0 = 0): pure elementwise
  k_e<<<(BB * NN * NN) / 256, 256, 0, stream>>>(cstb, zk, lam, xbuf, ybuf);
  // forward of y1
  k_p1<<<BB * CC * NN / 4, 256, 0, stream>>>(ybuf, csm, W1);
  // iterations 2..20
  for (int i = 1; i < NITER; ++i) {
    k_p2<<<BB * CC * (NN / 8), 256, 0, stream>>>(W1, maskPT);
    k_p31<<<BB * NN, 256, 0, stream>>>(W1, csm, cstb, zk, lam, xbuf, ybuf,
                                       betas[i], (i < NITER - 1) ? 1 : 0);
  }
  k_out<<<(BB * NN * NN) / 256, 256, 0, stream>>>(xbuf, out);
}

// Round 4
// 2630.760 us; speedup vs baseline: 1.2276x; 1.2276x over previous
//
#include <hip/hip_runtime.h>
#include <math.h>

// FISTA data-consistency with masked multi-coil 2D FFT operator.
// B=4, C=16, H=W=384.
// Register FFT: 384 = 6 (regs) x 64 (lanes); DIF leaves bit-reversed-permuted
// frequencies; mask is pre-permuted; DIT consumes permuted order (free).
// Loop: iter-1 elementwise (y0=0); 19 rounds of p1/p2/p3; out fused in last p3.
// R3 lesson: do NOT fuse p3+p1 (VGPR 144 -> 11% occupancy, csm streamed 2x).

#define NN 384
#define BB 4
#define CC 16
#define NITER 20
#define LNPAD 432   // old LDS path (precompute only)

__device__ __forceinline__ int LID(int i) { return i + (i >> 3); }

__device__ __forceinline__ float2 cmulf(float2 a, float2 b) {
  return make_float2(a.x * b.x - a.y * b.y, a.x * b.y + a.y * b.x);
}

template<int DIR>
__device__ __forceinline__ void dft4(float2* v) {
  float ax = v[0].x + v[2].x, ay = v[0].y + v[2].y;
  float bx = v[0].x - v[2].x, by = v[0].y - v[2].y;
  float cx = v[1].x + v[3].x, cy = v[1].y + v[3].y;
  float dx = v[1].x - v[3].x, dy = v[1].y - v[3].y;
  float dix, diy;
  if (DIR < 0) { dix = dy; diy = -dx; }
  else         { dix = -dy; diy = dx; }
  v[0] = make_float2(ax + cx, ay + cy);
  v[2] = make_float2(ax - cx, ay - cy);
  v[1] = make_float2(bx + dix, by + diy);
  v[3] = make_float2(bx - dix, by - diy);
}

template<int DIR>
__device__ __forceinline__ void dft6(float2* v) {
  const float S3 = 0.86602540378443864676f;
  const float wc[6]  = {1.f, 0.5f, -0.5f, -1.f, -0.5f, 0.5f};
  const float wsf[6] = {0.f, -S3, -S3, 0.f, S3, S3};  // forward (e^{-2pi i k/6})
  float2 o[6];
#pragma unroll
  for (int k = 0; k < 6; ++k) {
    float ox = v[0].x, oy = v[0].y;
#pragma unroll
    for (int r = 1; r < 6; ++r) {
      int idx = (r * k) % 6;
      float wr_ = wc[idx];
      float wi_ = (DIR < 0) ? wsf[idx] : -wsf[idx];
      ox += v[r].x * wr_ - v[r].y * wi_;
      oy += v[r].x * wi_ + v[r].y * wr_;
    }
    o[k] = make_float2(ox, oy);
  }
#pragma unroll
  for (int k = 0; k < 6; ++k) v[k] = o[k];
}

// ---------------- register FFT machinery (iteration path) ------------------

// radix-2 DIF FFT-64 across lanes; natural in -> bit-reversed out.
// Rolling twiddle: tw_h = exp(i*SIGN*pi*(t&(h-1))/h); tw_{h/2} = +-tw_h^2
// (sign = -1 iff t&(h/2)); only ONE __sincosf for the whole transform.
template<int SIGN>
__device__ __forceinline__ void dif64(float2 v[6], int t) {
  float ang = (float)SIGN * (3.14159265358979323846f / 32.0f) * (float)(t & 31);
  float2 tw; __sincosf(ang, &tw.y, &tw.x);
#pragma unroll
  for (int hs = 5; hs >= 0; --hs) {
    int h = 1 << hs;
    bool hi = (t & h) != 0;
    float cs = tw.x, sn = tw.y;
#pragma unroll
    for (int r = 0; r < 6; ++r) {
      float2 o;
      o.x = __shfl_xor(v[r].x, h);
      o.y = __shfl_xor(v[r].y, h);
      float dx = o.x - v[r].x, dy = o.y - v[r].y;
      float2 twv = make_float2(dx * cs - dy * sn, dx * sn + dy * cs);
      v[r] = hi ? twv : make_float2(v[r].x + o.x, v[r].y + o.y);
    }
    if (hs > 0) {
      float sqx = tw.x * tw.x - tw.y * tw.y;
      float sqy = 2.0f * tw.x * tw.y;
      bool neg = (t & (h >> 1)) != 0;
      tw.x = neg ? -sqx : sqx;
      tw.y = neg ? -sqy : sqy;
    }
  }
}

// radix-2 DIT FFT-64 across lanes; bit-reversed in -> natural out.
// Stages h=1 (tw=1) and h=2 (tw in {1, +-i}) need no sincos.
template<int SIGN>
__device__ __forceinline__ void dit64(float2 v[6], int t) {
#pragma unroll
  for (int hs = 0; hs < 6; ++hs) {
    int h = 1 << hs;
    float cs, sn;
    if (hs == 0) { cs = 1.0f; sn = 0.0f; }
    else if (hs == 1) {
      bool o = (t & 1) != 0;
      cs = o ? 0.0f : 1.0f;
      sn = o ? (float)SIGN : 0.0f;
    } else {
      float ang = (float)SIGN * 3.14159265358979323846f / (float)h * (float)(t & (h - 1));
      __sincosf(ang, &sn, &cs);
    }
    bool hi = (t & h) != 0;
#pragma unroll
    for (int r = 0; r < 6; ++r) {
      float2 bt = v[r];
      if (hi) bt = make_float2(v[r].x * cs - v[r].y * sn, v[r].x * sn + v[r].y * cs);
      float2 o;
      o.x = __shfl_xor(bt.x, h);
      o.y = __shfl_xor(bt.y, h);
      v[r] = hi ? make_float2(o.x - bt.x, o.y - bt.y)
                : make_float2(bt.x + o.x, bt.y + o.y);
    }
  }
}

// FWD: natural input (v[k]=x[t+64k]) -> permuted output (s=t+64r holds X[P(s)])
template<int SIGN>
__device__ __forceinline__ void fwd384(float2 v[6], int t) {
  dft6<SIGN>(v);
  float ang = (float)SIGN * 6.28318530717958647692f / 384.0f * (float)t;
  float sn, cs; __sincosf(ang, &sn, &cs);
  float2 w = make_float2(cs, sn), wr = w;
#pragma unroll
  for (int r = 1; r < 6; ++r) { v[r] = cmulf(v[r], wr); wr = cmulf(wr, w); }
  dif64<SIGN>(v, t);
}

// BWD: permuted input -> natural output; unnormalized inverse of fwd384.
template<int SIGN>
__device__ __forceinline__ void bwd384(float2 v[6], int t) {
  dit64<SIGN>(v, t);
  float ang = (float)SIGN * 6.28318530717958647692f / 384.0f * (float)t;
  float sn, cs; __sincosf(ang, &sn, &cs);
  float2 w = make_float2(cs, sn), wr = w;
#pragma unroll
  for (int r = 1; r < 6; ++r) { v[r] = cmulf(v[r], wr); wr = cmulf(wr, w); }
  dft6<SIGN>(v);
}

// ---------------- old LDS fft384 (precompute kernels only) -----------------
template<int R, int NS, int DIR>
__device__ __forceinline__ void fft_stage(const float2* S, float2* D, int t) {
  constexpr int NR = NN / R;
  constexpr float TWOPI = 6.28318530717958647692f;
#pragma unroll
  for (int rep = 0; rep < (NR + 63) / 64; ++rep) {
    int j = t + rep * 64;
    if (j < NR) {
      float2 v[R];
#pragma unroll
      for (int r = 0; r < R; ++r) v[r] = S[LID(j + r * NR)];
      if constexpr (NS > 1) {
        float ang = (float)DIR * (TWOPI / (float)(NS * R)) * (float)(j % NS);
        float sv, cv;
        __sincosf(ang, &sv, &cv);
        float2 w = make_float2(cv, sv);
        float2 wr = w;
#pragma unroll
        for (int r = 1; r < R; ++r) { v[r] = cmulf(v[r], wr); wr = cmulf(wr, w); }
      }
      if constexpr (R == 4) dft4<DIR>(v); else dft6<DIR>(v);
      int base = (j / NS) * (NS * R) + (j % NS);
#pragma unroll
      for (int r = 0; r < R; ++r) D[LID(base + r * NS)] = v[r];
    }
  }
}

template<int DIR>
__device__ __forceinline__ void fft384(float2* A, float2* Bf, int t) {
  fft_stage<4, 1,  DIR>(A,  Bf, t); __syncthreads();
  fft_stage<4, 4,  DIR>(Bf, A,  t); __syncthreads();
  fft_stage<4, 16, DIR>(A,  Bf, t); __syncthreads();
  fft_stage<6, 64, DIR>(Bf, A,  t); __syncthreads();
}

// ---------------- E: iteration 1 (y0 = 0 -> grad = -cst), elementwise ------
__global__ __launch_bounds__(256) void k_e(const float2* __restrict__ cstb,
                                           const float* __restrict__ zk,
                                           const float* __restrict__ lamp,
                                           float2* __restrict__ xbuf,
                                           float2* __restrict__ ybuf) {
  long i = (long)blockIdx.x * 256 + threadIdx.x;
  long b = i / (NN * NN);
  long p = i % (NN * NN);
  float lamv = lamp[0];
  float2 cs = cstb[i];
  float zr = zk[(b * 2 + 0) * (long)(NN * NN) + p];
  float zi = zk[(b * 2 + 1) * (long)(NN * NN) + p];
  float xr = cs.x - lamv * (cs.x - zr);
  float xi = cs.y - lamv * (cs.y - zi);
  xr = fmaxf(xr, 0.f);
  xi = fmaxf(xi, 0.f);
  float2 x = make_float2(xr, xi);
  xbuf[i] = x;
  ybuf[i] = x;   // t1 = 1 -> y1 = x1
}

// ---------------- P1: row FFT of coil*y -> W1 (permuted-x storage) ---------
// grid B*C*384/4, 256 thr; one wave per row; no LDS, no barriers.
__global__ __launch_bounds__(256) void k_p1(const float2* __restrict__ ybuf,
                                            const float* __restrict__ csm,
                                            float2* __restrict__ W1) {
  int t = threadIdx.x & 63;
  int w = threadIdx.x >> 6;
  long gl = (long)blockIdx.x * 4 + w;       // (b*C + c)*384 + y
  int y = (int)(gl % NN);
  long bc = gl / NN;
  long b = bc >> 4, c = bc & 15;
  long rowoff = (long)y * NN;
  const float2* yrow = ybuf + b * (long)(NN * NN) + rowoff;
  const float* crow_re = csm + (b * 2 * CC + c) * (long)(NN * NN) + rowoff;
  const float* crow_im = crow_re + (long)CC * NN * NN;
  float2 v[6];
#pragma unroll
  for (int k = 0; k < 6; ++k) {
    int x = t + 64 * k;
    float2 yv = yrow[x];
    float cre = crow_re[x], cim = crow_im[x];
    v[k] = make_float2(yv.x * cre - yv.y * cim, yv.x * cim + yv.y * cre);
  }
  fwd384<-1>(v, t);
  float2* orow = W1 + gl * NN;
#pragma unroll
  for (int r = 0; r < 6; ++r) orow[t + 64 * r] = v[r];
}

// ---------------- P2: col FFT -> mask -> col IFFT, in-place on W1 ----------
// grid B*C*(N/8), 256 thr. 8-column planar transpose tile (24.9 KB LDS).
// Each wave owns 2 disjoint columns -> exactly 2 __syncthreads per block.
#define P2PAD 389
__global__ __launch_bounds__(256) void k_p2(float2* __restrict__ W1,
                                            const unsigned char* __restrict__ maskPT) {
  __shared__ float ldsR[8][P2PAD];
  __shared__ float ldsI[8][P2PAD];
  int tid = threadIdx.x;
  int xt = blockIdx.x % (NN / 8);
  long bc = blockIdx.x / (NN / 8);
  long b = bc >> 4;
  int s0 = xt * 8;
  long sbase = bc * (long)(NN * NN);
#pragma unroll
  for (int k = 0; k < 12; ++k) {
    int e = tid + k * 256; int y = e >> 3; int c = e & 7;
    float2 val = W1[sbase + (long)y * NN + s0 + c];
    ldsR[c][y] = val.x; ldsI[c][y] = val.y;
  }
  __syncthreads();
  int w = tid >> 6, t = tid & 63;
  const unsigned char* mb = maskPT + b * (long)(NN * NN);
#pragma unroll
  for (int i = 0; i < 2; ++i) {
    int c = w * 2 + i;
    float2 v[6];
#pragma unroll
    for (int k = 0; k < 6; ++k)
      v[k] = make_float2(ldsR[c][t + 64 * k], ldsI[c][t + 64 * k]);
    fwd384<-1>(v, t);
    const unsigned char* mcol = mb + (long)(s0 + c) * NN;
#pragma unroll
    for (int r = 0; r < 6; ++r) {
      float mv = (float)mcol[t + 64 * r];
      v[r].x *= mv; v[r].y *= mv;
    }
    bwd384<1>(v, t);
#pragma unroll
    for (int k = 0; k < 6; ++k) {
      ldsR[c][t + 64 * k] = v[k].x * (1.0f / NN);
      ldsI[c][t + 64 * k] = v[k].y * (1.0f / NN);
    }
  }
  __syncthreads();
#pragma unroll
  for (int k = 0; k < 12; ++k) {
    int e = tid + k * 256; int y = e >> 3; int c = e & 7;
    W1[sbase + (long)y * NN + s0 + c] = make_float2(ldsR[c][y], ldsI[c][y]);
  }
}

// ---------------- P3: row IFFT + conj(coil) reduce + FISTA update ----------
// grid B*384 blocks, 256 thr; wave w handles coils 4w..4w+3; LDS reduce.
// last!=0: write planar output instead of x/y (final iteration).
__global__ __launch_bounds__(256) void k_p3(const float2* __restrict__ W1,
                                            const float* __restrict__ csm,
                                            const float2* __restrict__ cstb,
                                            const float* __restrict__ zk,
                                            const float* __restrict__ lamp,
                                            float2* __restrict__ xbuf,
                                            float2* __restrict__ ybuf,
                                            float* __restrict__ outp,
                                            float beta, int last) {
  __shared__ float2 part[4][NN];
  int tid = threadIdx.x;
  int w = tid >> 6, t = tid & 63;
  long gl = blockIdx.x;            // b*384 + y
  long b = gl / NN;
  int y = (int)(gl % NN);
  long rowoff = (long)y * NN;
  float2 acc[6];
#pragma unroll
  for (int k = 0; k < 6; ++k) acc[k] = make_float2(0.f, 0.f);
#pragma unroll
  for (int ci = 0; ci < 4; ++ci) {
    int c = w * 4 + ci;
    const float2* row = W1 + ((b * CC + c) * (long)NN + y) * NN;
    float2 v[6];
#pragma unroll
    for (int r = 0; r < 6; ++r) v[r] = row[t + 64 * r];
    bwd384<1>(v, t);
    const float* cre = csm + (b * 2 * CC + c) * (long)(NN * NN) + rowoff;
    const float* cim = cre + (long)CC * NN * NN;
#pragma unroll
    for (int k = 0; k < 6; ++k) {
      int x = t + 64 * k;
      float a = cre[x], bb = cim[x];
      acc[k].x += (a * v[k].x + bb * v[k].y);
      acc[k].y += (a * v[k].y - bb * v[k].x);
    }
  }
#pragma unroll
  for (int k = 0; k < 6; ++k) part[w][t + 64 * k] = acc[k];
  __syncthreads();
  float lamv = lamp[0];
  long pbase = b * (long)(NN * NN) + rowoff;
  for (int e = tid; e < NN; e += 256) {
    float Qx = (part[0][e].x + part[1][e].x + part[2][e].x + part[3][e].x) * (1.0f / NN);
    float Qy = (part[0][e].y + part[1][e].y + part[2][e].y + part[3][e].y) * (1.0f / NN);
    float2 yv = ybuf[pbase + e];
    float2 cs = cstb[pbase + e];
    float zr = zk[(b * 2 + 0) * (long)(NN * NN) + rowoff + e];
    float zi = zk[(b * 2 + 1) * (long)(NN * NN) + rowoff + e];
    float xr = yv.x - (Qx - cs.x);
    float xi = yv.y - (Qy - cs.y);
    xr = xr - lamv * (xr - zr);
    xi = xi - lamv * (xi - zi);
    xr = fmaxf(xr, 0.f);
    xi = fmaxf(xi, 0.f);
    if (last) {
      outp[(b * 2 + 0) * (long)(NN * NN) + rowoff + e] = xr;
      outp[(b * 2 + 1) * (long)(NN * NN) + rowoff + e] = xi;
    } else {
      float2 xo = xbuf[pbase + e];
      xbuf[pbase + e] = make_float2(xr, xi);
      ybuf[pbase + e] = make_float2(xr + beta * (xr - xo.x), xi + beta * (xi - xo.y));
    }
  }
}

// ---------------- mask permutation precompute (one-time) -------------------
// maskPT[b][sx][sy] = mask[b][P(sy)][P(sx)], P(s) = (s>>6) + 6*brev6(s&63)
__global__ __launch_bounds__(256) void k_mpre(const int* __restrict__ mask,
                                              unsigned char* __restrict__ maskPT) {
  long i = (long)blockIdx.x * 256 + threadIdx.x;
  long b = i / (NN * NN);
  int rem = (int)(i % (NN * NN));
  int sx = rem / NN, sy = rem % NN;
  int fx = (sx >> 6) + 6 * (int)(__brev((unsigned)(sx & 63)) >> 26);
  int fy = (sy >> 6) + 6 * (int)(__brev((unsigned)(sy & 63)) >> 26);
  maskPT[i] = (unsigned char)mask[b * (long)(NN * NN) + (long)fy * NN + fx];
}

// ---------------- precompute: cst = (sum_c conj(coil)) * IFFT2(m*b) --------
__global__ __launch_bounds__(256) void k_preA(const float* __restrict__ x0,
                                              const int* __restrict__ mask,
                                              float2* __restrict__ T) {
  __shared__ float2 U[4][LNPAD], V[4][LNPAD];
  int tid = threadIdx.x;
  int line = tid >> 6, t = tid & 63;
  long gl0 = (long)blockIdx.x * 4;
#pragma unroll
  for (int k = 0; k < 6; ++k) {
    int e = tid + k * 256; int l = e / NN; int x = e % NN;
    long gl = gl0 + l;
    long b = gl / NN;
    int y = (int)(gl % NN);
    long pidx = (long)y * NN + x;
    float mv = (float)mask[b * (long)(NN * NN) + pidx];
    float br = x0[(b * 2 + 0) * (long)(NN * NN) + pidx] * mv;
    float bi = x0[(b * 2 + 1) * (long)(NN * NN) + pidx] * mv;
    U[l][LID(x)] = make_float2(br, bi);
  }
  __syncthreads();
  fft384<1>(U[line], V[line], t);
#pragma unroll
  for (int k = 0; k < 6; ++k) {
    int e = tid + k * 256; int l = e / NN; int x = e % NN;
    float2 u = U[l][LID(x)];
    T[(gl0 + l) * NN + x] = make_float2(u.x * (1.0f / NN), u.y * (1.0f / NN));
  }
}

__global__ __launch_bounds__(256) void k_preB(const float2* __restrict__ T,
                                              float2* __restrict__ r0) {
  __shared__ float2 tile[NN][17];
  __shared__ float2 U[4][LNPAD], V[4][LNPAD];
  int tid = threadIdx.x;
  int xt = blockIdx.x % (NN / 16);
  long b = blockIdx.x / (NN / 16);
  int x0c = xt * 16;
  long sbase = b * (long)(NN * NN);
#pragma unroll
  for (int k = 0; k < 24; ++k) {
    int e = tid + k * 256; int y = e >> 4; int c = e & 15;
    tile[y][c] = T[sbase + (long)y * NN + x0c + c];
  }
  __syncthreads();
  int line = tid >> 6, t = tid & 63;
  for (int g = 0; g < 4; ++g) {
#pragma unroll
    for (int k = 0; k < 6; ++k) {
      int e = tid + k * 256; int l = e / NN; int y = e % NN;
      U[l][LID(y)] = tile[y][4 * g + l];
    }
    __syncthreads();
    fft384<1>(U[line], V[line], t);
#pragma unroll
    for (int k = 0; k < 6; ++k) {
      int e = tid + k * 256; int l = e / NN; int y = e % NN;
      float2 u = U[l][LID(y)];
      tile[y][4 * g + l] = make_float2(u.x * (1.0f / NN), u.y * (1.0f / NN));
    }
    __syncthreads();
  }
#pragma unroll
  for (int k = 0; k < 24; ++k) {
    int e = tid + k * 256; int y = e >> 4; int c = e & 15;
    r0[sbase + (long)y * NN + x0c + c] = tile[y][c];
  }
}

__global__ __launch_bounds__(256) void k_preC(const float* __restrict__ csm,
                                              const float2* __restrict__ r0,
                                              float2* __restrict__ cstb) {
  long i = (long)blockIdx.x * 256 + threadIdx.x;
  long b = i / (NN * NN);
  long p = i % (NN * NN);
  float sr = 0.f, si = 0.f;
#pragma unroll
  for (int c = 0; c < CC; ++c) {
    sr += csm[(b * 2 * CC + c) * (long)(NN * NN) + p];
    si -= csm[((b * 2 + 1) * CC + c) * (long)(NN * NN) + p];
  }
  float2 r = r0[i];
  cstb[i] = make_float2(sr * r.x - si * r.y, sr * r.y + si * r.x);
}

extern "C" void kernel_launch(void* const* d_in, const int* in_sizes, int n_in,
                              void* d_out, int out_size, void* d_ws, size_t ws_size,
                              hipStream_t stream) {
  const float* zk  = (const float*)d_in[0];
  const float* x0  = (const float*)d_in[1];
  const float* csm = (const float*)d_in[2];
  const float* lam = (const float*)d_in[3];
  const int*   msk = (const int*)d_in[4];
  float* out = (float*)d_out;

  // ws layout (float2 units): W1 [B*C*N*N] | y | x | cst | maskPT(uchar)
  size_t img = (size_t)BB * NN * NN;
  float2* W1   = (float2*)d_ws;
  float2* ybuf = W1 + (size_t)BB * CC * NN * NN;
  float2* xbuf = ybuf + img;
  float2* cstb = xbuf + img;
  unsigned char* maskPT = (unsigned char*)(cstb + img);
  float2* T  = W1;        // precompute scratch overlays W1
  float2* r0 = W1 + img;

  double tcur = 1.0;
  float betas[NITER];
  for (int i = 0; i < NITER; ++i) {
    double tn = (1.0 + sqrt(1.0 + 4.0 * tcur * tcur)) * 0.5;
    betas[i] = (float)((tcur - 1.0) / tn);
    tcur = tn;
  }

  k_mpre<<<(BB * NN * NN) / 256, 256, 0, stream>>>(msk, maskPT);
  k_preA<<<BB * NN / 4, 256, 0, stream>>>(x0, msk, T);
  k_preB<<<BB * (NN / 16), 256, 0, stream>>>(T, r0);
  k_preC<<<(BB * NN * NN) / 256, 256, 0, stream>>>(csm, r0, cstb);
  // iteration 1 (y0 = 0): pure elementwise
  k_e<<<(BB * NN * NN) / 256, 256, 0, stream>>>(cstb, zk, lam, xbuf, ybuf);
  // iterations 2..20: forward, mask round-trip, adjoint+update
  for (int i = 1; i < NITER; ++i) {
    k_p1<<<BB * CC * NN / 4, 256, 0, stream>>>(ybuf, csm, W1);
    k_p2<<<BB * CC * (NN / 8), 256, 0, stream>>>(W1, maskPT);
    k_p3<<<BB * NN, 256, 0, stream>>>(W1, csm, cstb, zk, lam, xbuf, ybuf, out,
                                      betas[i], (i == NITER - 1) ? 1 : 0);
  }
}